// Round 2
// baseline (1297.868 us; speedup 1.0000x reference)
//
#include <hip/hip_runtime.h>
#include <math.h>

#define T_LEN 4096
#define C_DIM 768
#define H_NUM 12
#define D_DIM 64

// ---------------------------------------------------------------------------
// Projection GEMM: out[h][t][d] = sum_c x[t][c] * W[c][h*64+d] + b[h*64+d]
// M=4096, N=768, K=768. BM=64, BN=64, BK=32, 256 threads, 4x4 micro-tile.
// blockIdx.z = 0 -> (Wk,bk)->kout ; 1 -> (Wq,bq)->qout.
// Output layout [H][T][D] so attention reads contiguous 64-float rows.
// ---------------------------------------------------------------------------
__global__ __launch_bounds__(256) void proj_gemm(
    const float* __restrict__ x,
    const float* __restrict__ Wk, const float* __restrict__ bk,
    const float* __restrict__ Wq, const float* __restrict__ bq,
    float* __restrict__ kout, float* __restrict__ qout) {

    const float* W;
    const float* bias;
    float* out;
    if (blockIdx.z == 0) { W = Wk; bias = bk; out = kout; }
    else                 { W = Wq; bias = bq; out = qout; }

    // +4 pad: keeps rows 16B-aligned (68*4=272B, /16 ok) and breaks the
    // 4-way write conflict of the transposed A staging.
    __shared__ __align__(16) float As[32][68];  // [k][m]
    __shared__ __align__(16) float Bs[32][68];  // [k][n]

    const int tid = threadIdx.x;
    const int m0_blk = blockIdx.y * 64;
    const int n0_blk = blockIdx.x * 64;

    // micro-tile: tx = tid%16 (cols), ty = tid/16 (rows)
    const int tx = tid & 15, ty = tid >> 4;
    const int mm = ty * 4;
    const int nn = tx * 4;

    float acc[4][4] = {};

    // A load: lane -> (a_m row, a_kq*4 k-offset); 8 lanes cover one 128B row seg
    const int a_kq = tid & 7;
    const int a_m  = tid >> 3;       // 0..31, two halves of 64 rows
    // B load: 16 lanes cover one 256B row segment
    const int b_n4 = (tid & 15) * 4;
    const int b_k  = tid >> 4;       // 0..15, two halves of 32 k

    for (int k0 = 0; k0 < C_DIM; k0 += 32) {
#pragma unroll
        for (int half = 0; half < 2; ++half) {
            const int m = a_m + half * 32;
            const float4 av = *reinterpret_cast<const float4*>(
                &x[(size_t)(m0_blk + m) * C_DIM + k0 + a_kq * 4]);
            As[a_kq * 4 + 0][m] = av.x;
            As[a_kq * 4 + 1][m] = av.y;
            As[a_kq * 4 + 2][m] = av.z;
            As[a_kq * 4 + 3][m] = av.w;
        }
#pragma unroll
        for (int half = 0; half < 2; ++half) {
            const int kk = b_k + half * 16;
            *reinterpret_cast<float4*>(&Bs[kk][b_n4]) =
                *reinterpret_cast<const float4*>(
                    &W[(size_t)(k0 + kk) * C_DIM + n0_blk + b_n4]);
        }
        __syncthreads();

#pragma unroll
        for (int kk = 0; kk < 32; ++kk) {
            const float4 a4 = *reinterpret_cast<const float4*>(&As[kk][mm]);
            const float4 b4 = *reinterpret_cast<const float4*>(&Bs[kk][nn]);
            const float a_[4] = {a4.x, a4.y, a4.z, a4.w};
            const float b_[4] = {b4.x, b4.y, b4.z, b4.w};
#pragma unroll
            for (int i = 0; i < 4; ++i)
#pragma unroll
                for (int j = 0; j < 4; ++j)
                    acc[i][j] = fmaf(a_[i], b_[j], acc[i][j]);
        }
        __syncthreads();
    }

    // epilogue: head h == blockIdx.x (BN == D == 64), local dim = nn..nn+3
    const int h = blockIdx.x;
    const float4 bv = *reinterpret_cast<const float4*>(&bias[n0_blk + nn]);
    const float b_[4] = {bv.x, bv.y, bv.z, bv.w};
#pragma unroll
    for (int i = 0; i < 4; ++i) {
        const int t = m0_blk + mm + i;
        float4 o;
        o.x = acc[i][0] + b_[0];
        o.y = acc[i][1] + b_[1];
        o.z = acc[i][2] + b_[2];
        o.w = acc[i][3] + b_[3];
        *reinterpret_cast<float4*>(&out[((size_t)h * T_LEN + t) * D_DIM + nn]) = o;
    }
}

// ---------------------------------------------------------------------------
// Flash-style causal attention with the reference's swapped roles:
//   S[i][j] = K_i . Q_j  (i = softmax row), mask j<=i, y_i = sum_j att * v_j
// One block per (head, 64-row block). 256 threads: quad of 4 lanes per row,
// each lane owns 16 of the 64 dims. Q/V tiles staged in LDS (quad-broadcast
// reads -> conflict free). Online softmax in 16-col chunks (static reg idx).
// ---------------------------------------------------------------------------
__global__ __launch_bounds__(256) void attn_kernel(
    const float* __restrict__ K,   // [H][T][64]
    const float* __restrict__ Q,   // [H][T][64]
    const float* __restrict__ x,   // [T][768] (V = raw x per head slice)
    float* __restrict__ y) {       // [T][768]

    const int h  = blockIdx.y;
    const int i0 = ((int)gridDim.x - 1 - (int)blockIdx.x) * 64;  // heavy blocks first
    const int tid  = threadIdx.x;
    const int r    = tid >> 2;      // 0..63 local row
    const int quad = tid & 3;       // 0..3
    const int row  = i0 + r;
    const int dbase = quad * 16;

    __shared__ __align__(16) float Qs[64 * 64];
    __shared__ __align__(16) float Vs[64 * 64];

    // K row fragment (16 dims) in registers
    const float* krow = &K[((size_t)h * T_LEN + row) * D_DIM + dbase];
    const float4 k0 = *reinterpret_cast<const float4*>(krow + 0);
    const float4 k1 = *reinterpret_cast<const float4*>(krow + 4);
    const float4 k2 = *reinterpret_cast<const float4*>(krow + 8);
    const float4 k3 = *reinterpret_cast<const float4*>(krow + 12);

    float acc[16] = {};
    float mrun = -1e30f, lrun = 0.0f;

    for (int j0 = 0; j0 <= i0; j0 += 64) {
        // ---- stage Q tile (contiguous 16KB) and V tile (strided rows) ----
        {
            const float* qsrc = &Q[((size_t)h * T_LEN + j0) * D_DIM];
#pragma unroll
            for (int it = 0; it < 4; ++it) {
                const int idx = tid + it * 256;  // float4 index 0..1023
                *reinterpret_cast<float4*>(&Qs[idx * 4]) =
                    *reinterpret_cast<const float4*>(&qsrc[idx * 4]);
            }
#pragma unroll
            for (int it = 0; it < 4; ++it) {
                const int jrow = (tid >> 4) + it * 16;
                const int part = tid & 15;
                *reinterpret_cast<float4*>(&Vs[jrow * 64 + part * 4]) =
                    *reinterpret_cast<const float4*>(
                        &x[(size_t)(j0 + jrow) * C_DIM + h * D_DIM + part * 4]);
            }
        }
        __syncthreads();

        const bool diag = (j0 == i0);

        for (int jc = 0; jc < 4; ++jc) {      // 16-col chunks
            float sj[16];
            float cmax = -1e30f;
#pragma unroll
            for (int j = 0; j < 16; ++j) {
                const int jj = jc * 16 + j;
                const float* qrow = &Qs[jj * D_DIM + dbase];
                const float4 q0 = *reinterpret_cast<const float4*>(qrow + 0);
                const float4 q1 = *reinterpret_cast<const float4*>(qrow + 4);
                const float4 q2 = *reinterpret_cast<const float4*>(qrow + 8);
                const float4 q3 = *reinterpret_cast<const float4*>(qrow + 12);
                float s = k0.x * q0.x;
                s = fmaf(k0.y, q0.y, s); s = fmaf(k0.z, q0.z, s); s = fmaf(k0.w, q0.w, s);
                s = fmaf(k1.x, q1.x, s); s = fmaf(k1.y, q1.y, s);
                s = fmaf(k1.z, q1.z, s); s = fmaf(k1.w, q1.w, s);
                s = fmaf(k2.x, q2.x, s); s = fmaf(k2.y, q2.y, s);
                s = fmaf(k2.z, q2.z, s); s = fmaf(k2.w, q2.w, s);
                s = fmaf(k3.x, q3.x, s); s = fmaf(k3.y, q3.y, s);
                s = fmaf(k3.z, q3.z, s); s = fmaf(k3.w, q3.w, s);
                // quad members are lanes differing in bits 0..1
                s += __shfl_xor(s, 1);
                s += __shfl_xor(s, 2);
                if (diag && jj > r) s = -1e30f;
                sj[j] = s;
                cmax = fmaxf(cmax, s);
            }
            const float newm = fmaxf(mrun, cmax);
            const float scale = __expf(mrun - newm);
            lrun *= scale;
#pragma unroll
            for (int d = 0; d < 16; ++d) acc[d] *= scale;
#pragma unroll
            for (int j = 0; j < 16; ++j) {
                const float p = __expf(sj[j] - newm);
                lrun += p;
                const int jj = jc * 16 + j;
                const float* vrow = &Vs[jj * D_DIM + dbase];
                const float4 v0 = *reinterpret_cast<const float4*>(vrow + 0);
                const float4 v1 = *reinterpret_cast<const float4*>(vrow + 4);
                const float4 v2 = *reinterpret_cast<const float4*>(vrow + 8);
                const float4 v3 = *reinterpret_cast<const float4*>(vrow + 12);
                acc[0]  = fmaf(p, v0.x, acc[0]);
                acc[1]  = fmaf(p, v0.y, acc[1]);
                acc[2]  = fmaf(p, v0.z, acc[2]);
                acc[3]  = fmaf(p, v0.w, acc[3]);
                acc[4]  = fmaf(p, v1.x, acc[4]);
                acc[5]  = fmaf(p, v1.y, acc[5]);
                acc[6]  = fmaf(p, v1.z, acc[6]);
                acc[7]  = fmaf(p, v1.w, acc[7]);
                acc[8]  = fmaf(p, v2.x, acc[8]);
                acc[9]  = fmaf(p, v2.y, acc[9]);
                acc[10] = fmaf(p, v2.z, acc[10]);
                acc[11] = fmaf(p, v2.w, acc[11]);
                acc[12] = fmaf(p, v3.x, acc[12]);
                acc[13] = fmaf(p, v3.y, acc[13]);
                acc[14] = fmaf(p, v3.z, acc[14]);
                acc[15] = fmaf(p, v3.w, acc[15]);
            }
            mrun = newm;
        }
        __syncthreads();
    }

    const float inv = 1.0f / lrun;
    float* ydst = &y[(size_t)row * C_DIM + h * D_DIM + dbase];
    float4 o;
    o.x = acc[0] * inv;  o.y = acc[1] * inv;  o.z = acc[2] * inv;  o.w = acc[3] * inv;
    *reinterpret_cast<float4*>(ydst + 0) = o;
    o.x = acc[4] * inv;  o.y = acc[5] * inv;  o.z = acc[6] * inv;  o.w = acc[7] * inv;
    *reinterpret_cast<float4*>(ydst + 4) = o;
    o.x = acc[8] * inv;  o.y = acc[9] * inv;  o.z = acc[10] * inv; o.w = acc[11] * inv;
    *reinterpret_cast<float4*>(ydst + 8) = o;
    o.x = acc[12] * inv; o.y = acc[13] * inv; o.z = acc[14] * inv; o.w = acc[15] * inv;
    *reinterpret_cast<float4*>(ydst + 12) = o;
}

// ---------------------------------------------------------------------------
extern "C" void kernel_launch(void* const* d_in, const int* in_sizes, int n_in,
                              void* d_out, int out_size, void* d_ws, size_t ws_size,
                              hipStream_t stream) {
    const float* x  = (const float*)d_in[0];
    const float* Wk = (const float*)d_in[1];
    const float* bk = (const float*)d_in[2];
    const float* Wq = (const float*)d_in[3];
    const float* bq = (const float*)d_in[4];
    float* out = (float*)d_out;

    float* kbuf = (float*)d_ws;                                  // [H][T][64]
    float* qbuf = kbuf + (size_t)H_NUM * T_LEN * D_DIM;          // [H][T][64]

    dim3 g1(C_DIM / 64, T_LEN / 64, 2);   // (12, 64, 2)
    proj_gemm<<<g1, 256, 0, stream>>>(x, Wk, bk, Wq, bq, kbuf, qbuf);

    dim3 g2(T_LEN / 64, H_NUM);           // (64, 12)
    attn_kernel<<<g2, 256, 0, stream>>>(kbuf, qbuf, x, out);
}

// Round 3
// 376.968 us; speedup vs baseline: 3.4429x; 3.4429x over previous
//
#include <hip/hip_runtime.h>
#include <hip/hip_bf16.h>
#include <math.h>

#define T_LEN 4096
#define C_DIM 768
#define H_NUM 12
#define D_DIM 64

typedef __bf16 bf16x8 __attribute__((ext_vector_type(8)));
typedef float f32x16 __attribute__((ext_vector_type(16)));

static __device__ __forceinline__ unsigned short bf16bits(float f) {
    return __builtin_bit_cast(unsigned short, __float2bfloat16(f));
}

// ---------------------------------------------------------------------------
// Projection GEMM (fp32 compute, bf16 output [H][T][64]).
// M=4096, N=768, K=768. BM=64, BN=64, BK=32, 256 threads, 4x4 micro-tile.
// blockIdx.z = 0 -> (Wk,bk)->kout ; 1 -> (Wq,bq)->qout.
// ---------------------------------------------------------------------------
__global__ __launch_bounds__(256) void proj_gemm(
    const float* __restrict__ x,
    const float* __restrict__ Wk, const float* __restrict__ bk,
    const float* __restrict__ Wq, const float* __restrict__ bq,
    __hip_bfloat16* __restrict__ kout, __hip_bfloat16* __restrict__ qout) {

    const float* W;
    const float* bias;
    __hip_bfloat16* out;
    if (blockIdx.z == 0) { W = Wk; bias = bk; out = kout; }
    else                 { W = Wq; bias = bq; out = qout; }

    __shared__ __align__(16) float As[32][68];  // [k][m], +4 pad
    __shared__ __align__(16) float Bs[32][68];  // [k][n]

    const int tid = threadIdx.x;
    const int m0_blk = blockIdx.y * 64;
    const int n0_blk = blockIdx.x * 64;

    const int tx = tid & 15, ty = tid >> 4;
    const int mm = ty * 4;
    const int nn = tx * 4;

    float acc[4][4] = {};

    const int a_kq = tid & 7;
    const int a_m  = tid >> 3;
    const int b_n4 = (tid & 15) * 4;
    const int b_k  = tid >> 4;

    for (int k0 = 0; k0 < C_DIM; k0 += 32) {
#pragma unroll
        for (int half = 0; half < 2; ++half) {
            const int m = a_m + half * 32;
            const float4 av = *reinterpret_cast<const float4*>(
                &x[(size_t)(m0_blk + m) * C_DIM + k0 + a_kq * 4]);
            As[a_kq * 4 + 0][m] = av.x;
            As[a_kq * 4 + 1][m] = av.y;
            As[a_kq * 4 + 2][m] = av.z;
            As[a_kq * 4 + 3][m] = av.w;
        }
#pragma unroll
        for (int half = 0; half < 2; ++half) {
            const int kk = b_k + half * 16;
            *reinterpret_cast<float4*>(&Bs[kk][b_n4]) =
                *reinterpret_cast<const float4*>(
                    &W[(size_t)(k0 + kk) * C_DIM + n0_blk + b_n4]);
        }
        __syncthreads();

#pragma unroll
        for (int kk = 0; kk < 32; ++kk) {
            const float4 a4 = *reinterpret_cast<const float4*>(&As[kk][mm]);
            const float4 b4 = *reinterpret_cast<const float4*>(&Bs[kk][nn]);
            const float a_[4] = {a4.x, a4.y, a4.z, a4.w};
            const float b_[4] = {b4.x, b4.y, b4.z, b4.w};
#pragma unroll
            for (int i = 0; i < 4; ++i)
#pragma unroll
                for (int j = 0; j < 4; ++j)
                    acc[i][j] = fmaf(a_[i], b_[j], acc[i][j]);
        }
        __syncthreads();
    }

    const int h = blockIdx.x;   // BN == D == 64
    const float4 bv = *reinterpret_cast<const float4*>(&bias[n0_blk + nn]);
    const float b_[4] = {bv.x, bv.y, bv.z, bv.w};
#pragma unroll
    for (int i = 0; i < 4; ++i) {
        const int t = m0_blk + mm + i;
        ushort4 o;
        o.x = bf16bits(acc[i][0] + b_[0]);
        o.y = bf16bits(acc[i][1] + b_[1]);
        o.z = bf16bits(acc[i][2] + b_[2]);
        o.w = bf16bits(acc[i][3] + b_[3]);
        *reinterpret_cast<ushort4*>(
            &out[((size_t)h * T_LEN + t) * D_DIM + nn]) = o;
    }
}

// ---------------------------------------------------------------------------
// V transpose: Vt[h][d][t] = bf16(x[t][h*64+d]).  64x64 tiles via LDS.
// ---------------------------------------------------------------------------
__global__ __launch_bounds__(256) void vt_kernel(
    const float* __restrict__ x, __hip_bfloat16* __restrict__ Vt) {
    __shared__ float tile[64][65];
    const int t0 = blockIdx.x * 64;
    const int c0 = blockIdx.y * 64;
    const int tid = threadIdx.x;
    const int cl = tid & 63;
    const int rq = tid >> 6;
#pragma unroll
    for (int rr = 0; rr < 16; ++rr) {
        const int row = rr * 4 + rq;
        tile[row][cl] = x[(size_t)(t0 + row) * C_DIM + c0 + cl];
    }
    __syncthreads();
#pragma unroll
    for (int cc = 0; cc < 16; ++cc) {
        const int c = cc * 4 + rq;
        const int gc = c0 + c;
        const int h = gc >> 6, d = gc & 63;
        Vt[((size_t)h * D_DIM + d) * T_LEN + t0 + cl] =
            __float2bfloat16(tile[cl][c]);
    }
}

// ---------------------------------------------------------------------------
// MFMA flash attention (reference's swapped roles):
//   S[i][j] = K_i . Q_j  (softmax over j, j<=i),  y_i = sum_j att[i][j] V_j
// One wave per (head, 32-row i-tile). No LDS, no barriers; Q/K/V from L2.
// QK^T computed as S^T = mfma(A=Q_jtile, B=K_itile): lane holds col i=lane&31,
// 16 j-rows at crow(r,hi) = (r&3)+8*(r>>2)+4*(lane>>5)   [guide m74/m101].
// Defer-max (T13, THR=8): rescale of PV accumulator is a rare event.
// P -> bf16 words + shfl_xor(32) assembles the PV A-operand (T12 structure).
// ---------------------------------------------------------------------------
__global__ __launch_bounds__(256) void attn_mfma(
    const __hip_bfloat16* __restrict__ K,   // [H][T][64]
    const __hip_bfloat16* __restrict__ Q,   // [H][T][64]
    const __hip_bfloat16* __restrict__ Vt,  // [H][64][T]
    float* __restrict__ y) {                // [T][768]

    const int u  = blockIdx.x * 4 + (threadIdx.x >> 6);  // wave unit
    const int h  = u % H_NUM;
    const int itile = (T_LEN / 32 - 1) - u / H_NUM;      // heavy-first
    const int iw = itile * 32;
    const int lane = threadIdx.x & 63;
    const int lm = lane & 31;
    const int hi = lane >> 5;

    // K fragments (B-operand): lane holds K[iw+lm][ki*16 + 8*hi .. +7]
    const __hip_bfloat16* kp = K + ((size_t)h * T_LEN + iw + lm) * D_DIM + hi * 8;
    const bf16x8 bk0 = *reinterpret_cast<const bf16x8*>(kp + 0);
    const bf16x8 bk1 = *reinterpret_cast<const bf16x8*>(kp + 16);
    const bf16x8 bk2 = *reinterpret_cast<const bf16x8*>(kp + 32);
    const bf16x8 bk3 = *reinterpret_cast<const bf16x8*>(kp + 48);

    f32x16 acc0 = {};   // y[i][d=lm]      (d-tile 0)
    f32x16 acc1 = {};   // y[i][32+lm]     (d-tile 1)
    float m = -1e30f, lsum = 0.0f;

    const __hip_bfloat16* qrow  = Q  + ((size_t)h * T_LEN + lm) * D_DIM + hi * 8;
    const __hip_bfloat16* vrow0 = Vt + ((size_t)h * D_DIM + lm) * T_LEN + hi * 8;
    const __hip_bfloat16* vrow1 = vrow0 + (size_t)32 * T_LEN;

    for (int j0 = 0; j0 <= iw; j0 += 32) {
        // Q fragments (A-operand): lane holds Q[j0+lm][ki*16 + 8*hi .. +7]
        const __hip_bfloat16* qp = qrow + (size_t)j0 * D_DIM;
        const bf16x8 aq0 = *reinterpret_cast<const bf16x8*>(qp + 0);
        const bf16x8 aq1 = *reinterpret_cast<const bf16x8*>(qp + 16);
        const bf16x8 aq2 = *reinterpret_cast<const bf16x8*>(qp + 32);
        const bf16x8 aq3 = *reinterpret_cast<const bf16x8*>(qp + 48);

        f32x16 s = {};
        s = __builtin_amdgcn_mfma_f32_32x32x16_bf16(aq0, bk0, s, 0, 0, 0);
        s = __builtin_amdgcn_mfma_f32_32x32x16_bf16(aq1, bk1, s, 0, 0, 0);
        s = __builtin_amdgcn_mfma_f32_32x32x16_bf16(aq2, bk2, s, 0, 0, 0);
        s = __builtin_amdgcn_mfma_f32_32x32x16_bf16(aq3, bk3, s, 0, 0, 0);

        if (j0 == iw) {  // diagonal tile: mask j_rel > i_rel
#pragma unroll
            for (int r = 0; r < 16; ++r) {
                const int jr = (r & 3) + 8 * (r >> 2) + 4 * hi;
                if (jr > lm) s[r] = -1e30f;
            }
        }

        // per-column (i) max over all 32 j of this tile
        float pmax = s[0];
#pragma unroll
        for (int r = 1; r < 16; ++r) pmax = fmaxf(pmax, s[r]);
        pmax = fmaxf(pmax, __shfl_xor(pmax, 32));

        if (__any(pmax > m + 8.0f)) {   // rare: first tile + occasional growth
            const float mn = fmaxf(m, pmax);
            const float sc = __expf(m - mn);
            lsum *= sc;
#pragma unroll
            for (int r = 0; r < 16; ++r) {
                const float sr = __shfl(sc, (r & 3) + 8 * (r >> 2) + 4 * hi);
                acc0[r] *= sr;
                acc1[r] *= sr;
            }
            m = mn;
        }

        float p[16];
#pragma unroll
        for (int r = 0; r < 16; ++r) p[r] = __expf(s[r] - m);
        float ls = 0.0f;
#pragma unroll
        for (int r = 0; r < 16; ++r) ls += p[r];
        lsum += ls;

        // pack P to bf16 words: w[k] = (p[2k+1]<<16)|p[2k], rows crow(2k..2k+1)
        unsigned int w[8];
#pragma unroll
        for (int k = 0; k < 8; ++k)
            w[k] = (unsigned int)bf16bits(p[2 * k]) |
                   ((unsigned int)bf16bits(p[2 * k + 1]) << 16);
        unsigned int pw[8];
#pragma unroll
        for (int k = 0; k < 8; ++k) pw[k] = __shfl_xor((int)w[k], 32);

        // PV A-operand: lane holds P[i=lm][16*ks + 8*hi .. +7]
        const uint4 a0u = hi ? make_uint4(pw[2], pw[3], w[2], w[3])
                             : make_uint4(w[0], w[1], pw[0], pw[1]);
        const uint4 a1u = hi ? make_uint4(pw[6], pw[7], w[6], w[7])
                             : make_uint4(w[4], w[5], pw[4], pw[5]);
        const bf16x8 pa0 = __builtin_bit_cast(bf16x8, a0u);
        const bf16x8 pa1 = __builtin_bit_cast(bf16x8, a1u);

        // V fragments (B-operand): lane holds Vt[dt*32+lm][j0+16*ks+8*hi ..+7]
        const bf16x8 v00 = *reinterpret_cast<const bf16x8*>(vrow0 + j0 + 0);
        const bf16x8 v01 = *reinterpret_cast<const bf16x8*>(vrow0 + j0 + 16);
        const bf16x8 v10 = *reinterpret_cast<const bf16x8*>(vrow1 + j0 + 0);
        const bf16x8 v11 = *reinterpret_cast<const bf16x8*>(vrow1 + j0 + 16);

        acc0 = __builtin_amdgcn_mfma_f32_32x32x16_bf16(pa0, v00, acc0, 0, 0, 0);
        acc0 = __builtin_amdgcn_mfma_f32_32x32x16_bf16(pa1, v01, acc0, 0, 0, 0);
        acc1 = __builtin_amdgcn_mfma_f32_32x32x16_bf16(pa0, v10, acc1, 0, 0, 0);
        acc1 = __builtin_amdgcn_mfma_f32_32x32x16_bf16(pa1, v11, acc1, 0, 0, 0);
    }

    const float lt = lsum + __shfl_xor(lsum, 32);
    const float linv = 1.0f / lt;
#pragma unroll
    for (int r = 0; r < 16; ++r) {
        const int cr = (r & 3) + 8 * (r >> 2) + 4 * hi;
        const int row = iw + cr;
        const float li = __shfl(linv, cr);
        y[(size_t)row * C_DIM + h * D_DIM + lm]      = acc0[r] * li;
        y[(size_t)row * C_DIM + h * D_DIM + 32 + lm] = acc1[r] * li;
    }
}

// ---------------------------------------------------------------------------
extern "C" void kernel_launch(void* const* d_in, const int* in_sizes, int n_in,
                              void* d_out, int out_size, void* d_ws, size_t ws_size,
                              hipStream_t stream) {
    const float* x  = (const float*)d_in[0];
    const float* Wk = (const float*)d_in[1];
    const float* bk = (const float*)d_in[2];
    const float* Wq = (const float*)d_in[3];
    const float* bq = (const float*)d_in[4];
    float* out = (float*)d_out;

    __hip_bfloat16* kbuf = (__hip_bfloat16*)d_ws;                 // [H][T][64]
    __hip_bfloat16* qbuf = kbuf + (size_t)H_NUM * T_LEN * D_DIM;  // [H][T][64]
    __hip_bfloat16* vtbuf = qbuf + (size_t)H_NUM * T_LEN * D_DIM; // [H][64][T]

    dim3 g1(C_DIM / 64, T_LEN / 64, 2);   // (12, 64, 2)
    proj_gemm<<<g1, 256, 0, stream>>>(x, Wk, bk, Wq, bq, kbuf, qbuf);

    dim3 gv(T_LEN / 64, C_DIM / 64);      // (64, 12)
    vt_kernel<<<gv, 256, 0, stream>>>(x, vtbuf);

    const int nwaves = H_NUM * (T_LEN / 32);      // 1536
    attn_mfma<<<nwaves / 4, 256, 0, stream>>>(kbuf, qbuf, vtbuf, out);
}